// Round 1
// baseline (176.143 us; speedup 1.0000x reference)
//
#include <hip/hip_runtime.h>
#include <cstddef>

namespace {
constexpr int TOK   = 206;
constexpr int Bdim  = 256;
constexpr int Sdim  = 682;
constexpr int Tdim  = 2048;   // 3*682 + 2
constexpr int NROWS = Bdim * Sdim;   // 174592
}

__device__ __forceinline__ void argmax_upd(float v, int t, float& m, int& mi) {
    if (v > m) { m = v; mi = t; }
}

__global__ __launch_bounds__(256) void control_val_loss_main(
    const float* __restrict__ pred,
    const float* __restrict__ gt_acc,
    const float* __restrict__ gt_steer,
    const int*  __restrict__ gt_rev,
    double* __restrict__ ws)
{
    const int lane = threadIdx.x & 63;
    const int wid  = threadIdx.x >> 6;
    const int gw   = blockIdx.x * 4 + wid;
    const int nw   = gridDim.x * 4;

    float accS = 0.f, steerS = 0.f, revS = 0.f, cntS = 0.f;

    for (int row = gw; row < NROWS; row += nw) {
        const int b = row / Sdim;
        const int s = row - b * Sdim;
        const float* base = pred + ((size_t)b * Tdim + 3 * (size_t)s) * TOK;

        // 618 contiguous floats = 309 float2 (8B-aligned).
        // i2 = float2 index; lane's slots: lane, lane+64, lane+128, lane+192, lane+256
        const float2 v0 = *(const float2*)(base + 2 * lane);          // i2 [0,64)   : acc
        const float2 v1 = *(const float2*)(base + 2 * (lane + 64));   // i2 [64,128) : acc|steer
        const float2 v2 = *(const float2*)(base + 2 * (lane + 128));  // i2 [128,192): steer
        const float2 v3 = *(const float2*)(base + 2 * (lane + 192));  // i2 [192,256): steer|rev
        const bool hasV4 = (lane < 53);                               // i2 [256,309): rev
        float2 v4 = make_float2(0.f, 0.f);
        if (hasV4) v4 = *(const float2*)(base + 2 * (lane + 256));

        // ---- per-lane partials (indices ascend within lane -> strict > keeps first max)
        float aMax = v0.x; int aIdx = 2 * lane;
        argmax_upd(v0.y, 2 * lane + 1, aMax, aIdx);
        float sMax = -INFINITY; int sIdx = 0;
        {
            const int i2 = lane + 64;
            if (i2 < 103) {               // lanes 0..38: still acc
                argmax_upd(v1.x, 2 * i2,     aMax, aIdx);
                argmax_upd(v1.y, 2 * i2 + 1, aMax, aIdx);
            } else {                      // lanes 39..63: steer tokens 2*i2-206
                sMax = v1.x; sIdx = 2 * i2 - 206;
                argmax_upd(v1.y, sIdx + 1, sMax, sIdx);
            }
        }
        {
            const int t = 2 * (lane + 128) - 206;  // steer tokens [50,178)
            argmax_upd(v2.x, t,     sMax, sIdx);
            argmax_upd(v2.y, t + 1, sMax, sIdx);
        }
        float lo = 0.f, hi = 0.f;
        if (lane < 14) {                  // steer tokens [178,206)
            const int t = 2 * (lane + 192) - 206;
            argmax_upd(v3.x, t,     sMax, sIdx);
            argmax_upd(v3.y, t + 1, sMax, sIdx);
        } else {                          // rev tokens 2*lane-28, 2*lane-27 (all <= 99 -> lo)
            lo += __expf(v3.x) + __expf(v3.y);
        }
        if (hasV4) {                      // rev tokens 2*lane+100 (lo only for lane 0), 2*lane+101 (hi)
            const float ex = __expf(v4.x), ey = __expf(v4.y);
            if (lane == 0) lo += ex; else hi += ex;
            hi += ey;
        }

        // ---- wave butterflies (all lanes end with identical reduced values)
        #pragma unroll
        for (int off = 32; off > 0; off >>= 1) {
            const float oav = __shfl_xor(aMax, off);
            const int   oai = __shfl_xor(aIdx, off);
            if (oav > aMax || (oav == aMax && oai < aIdx)) { aMax = oav; aIdx = oai; }
            const float osv = __shfl_xor(sMax, off);
            const int   osi = __shfl_xor(sIdx, off);
            if (osv > sMax || (osv == sMax && osi < sIdx)) { sMax = osv; sIdx = osi; }
            lo += __shfl_xor(lo, off);
            hi += __shfl_xor(hi, off);
        }

        // ---- per-row losses
        const float Z   = lo + hi;
        const float pno = lo / Z;
        const float prv = hi / Z;
        const int   g   = gt_rev[row];
        const float ai  = (float)aIdx;
        const float si  = (float)sIdx;
        const float pa  = (ai > 101.0f) ? (ai / 101.0f - 1.0f) : (1.0f - ai / 101.0f);
        const float ps  = si / 101.0f - 1.0f;
        const float da  = pa - gt_acc[row];
        const float dsv = ps - gt_steer[row];
        const float ada = fabsf(da), ads = fabsf(dsv);
        accS   += (ada < 1.0f) ? 0.5f * da * da   : ada - 0.5f;
        steerS += (ads < 1.0f) ? 0.5f * dsv * dsv : ads - 0.5f;
        if (g != -100) {
            const float m2  = fmaxf(pno, prv);
            const float nll = (m2 + __logf(__expf(pno - m2) + __expf(prv - m2)))
                              - ((g == 0) ? pno : prv);
            revS += nll;
            cntS += 1.0f;
        }
    }

    __shared__ float red[4][4];
    if (lane == 0) {
        red[wid][0] = accS; red[wid][1] = steerS;
        red[wid][2] = revS; red[wid][3] = cntS;
    }
    __syncthreads();
    if (threadIdx.x == 0) {
        double a = 0, st = 0, r = 0, c = 0;
        for (int w = 0; w < 4; ++w) {
            a += red[w][0]; st += red[w][1]; r += red[w][2]; c += red[w][3];
        }
        atomicAdd(&ws[0], a);
        atomicAdd(&ws[1], st);
        atomicAdd(&ws[2], r);
        atomicAdd(&ws[3], c);
    }
}

__global__ void control_val_loss_final(const double* __restrict__ ws,
                                       float* __restrict__ out) {
    if (threadIdx.x == 0 && blockIdx.x == 0) {
        const double n = (double)NROWS;
        out[0] = (float)(ws[0] / n + ws[1] / n);
        out[1] = (float)(ws[2] / fmax(ws[3], 1.0));
    }
}

extern "C" void kernel_launch(void* const* d_in, const int* in_sizes, int n_in,
                              void* d_out, int out_size, void* d_ws, size_t ws_size,
                              hipStream_t stream) {
    const float* pred     = (const float*)d_in[0];
    const float* gt_acc   = (const float*)d_in[1];
    const float* gt_steer = (const float*)d_in[2];
    const int*   gt_rev   = (const int*)d_in[3];
    double* ws  = (double*)d_ws;
    float*  out = (float*)d_out;

    hipMemsetAsync(ws, 0, 4 * sizeof(double), stream);
    control_val_loss_main<<<2048, 256, 0, stream>>>(pred, gt_acc, gt_steer, gt_rev, ws);
    control_val_loss_final<<<1, 64, 0, stream>>>(ws, out);
}

// Round 2
// 148.053 us; speedup vs baseline: 1.1897x; 1.1897x over previous
//
#include <hip/hip_runtime.h>
#include <cstddef>

namespace {
constexpr int TOK   = 206;
constexpr int Sdim  = 682;
constexpr int Tdim  = 2048;              // 3*682 + 2
constexpr int NROWS = 256 * Sdim;        // 174592
constexpr int NG    = NROWS / 2;         // 87296 row-pairs
}

__global__ __launch_bounds__(256) void control_val_loss_main(
    const float* __restrict__ pred,
    const float* __restrict__ gt_acc,
    const float* __restrict__ gt_steer,
    const int*  __restrict__ gt_rev,
    double* __restrict__ ws)
{
    const int lane = threadIdx.x & 63;
    const int wid  = threadIdx.x >> 6;
    const int l32  = lane & 31;          // lane within half-wave
    const int h    = lane >> 5;          // which half -> which row of the pair
    const int gw   = blockIdx.x * 4 + wid;
    const int nw   = gridDim.x * 4;

    float accS = 0.f, steerS = 0.f, revS = 0.f, cntS = 0.f;

    for (int g = gw; g < NG; g += nw) {
        const int row = 2 * g + h;
        const unsigned b = (unsigned)row / 682u;                 // magic-mul
        // (b*2048 + 3s)*206 with s = row - 682b  ->  (3*row + 2*b)*206
        const float* base = pred + (size_t)(3u * (unsigned)row + 2u * b) * TOK;

        // 618 floats = 309 float2 (8B aligned). Half-wave covers slots
        // i2 = l32 + 32k, k=0..9 (k=9 only l32<21). 256B contiguous per
        // half per load instruction -> fully coalesced.
        float2 q[10];
        #pragma unroll
        for (int k = 0; k < 9; ++k)
            q[k] = *(const float2*)(base + 2 * (l32 + 32 * k));
        q[9] = make_float2(0.f, 0.f);
        if (l32 < 21) q[9] = *(const float2*)(base + 2 * (l32 + 288));

        // hoist tiny gt loads (uniform per half)
        const int   gt  = gt_rev[row];
        const float ga  = gt_acc[row];
        const float gs  = gt_steer[row];

        // ---- per-lane partials -------------------------------------------
        // acc tokens: k=0..2 all lanes; k=3 lanes l32<7
        float aM = q[0].x; int aI = 2 * l32;
        if (q[0].y > aM) { aM = q[0].y; aI = 2 * l32 + 1; }
        #pragma unroll
        for (int k = 1; k <= 2; ++k) {
            const int t = 2 * (l32 + 32 * k);
            if (q[k].x > aM) { aM = q[k].x; aI = t; }
            if (q[k].y > aM) { aM = q[k].y; aI = t + 1; }
        }
        float sM = -INFINITY; int sI = 0;
        {   // k=3: i2 in [96,128): acc if i2<103 else steer (token 2*i2-206)
            const int i2 = l32 + 96;
            if (l32 < 7) {
                if (q[3].x > aM) { aM = q[3].x; aI = 2 * i2; }
                if (q[3].y > aM) { aM = q[3].y; aI = 2 * i2 + 1; }
            } else {
                sM = q[3].x; sI = 2 * i2 - 206;
                if (q[3].y > sM) { sM = q[3].y; sI = 2 * i2 - 205; }
            }
        }
        #pragma unroll
        for (int k = 4; k <= 5; ++k) {   // steer tokens [50,178)
            const int st = 2 * (l32 + 32 * k) - 206;
            if (q[k].x > sM) { sM = q[k].x; sI = st; }
            if (q[k].y > sM) { sM = q[k].y; sI = st + 1; }
        }
        float lo = 0.f, hi = 0.f;
        {   // k=6: i2 in [192,224): steer if i2<206 (l32<14) else rev (all lo)
            if (l32 < 14) {
                const int st = 2 * (l32 + 192) - 206;
                if (q[6].x > sM) { sM = q[6].x; sI = st; }
                if (q[6].y > sM) { sM = q[6].y; sI = st + 1; }
            } else {
                lo += __expf(q[6].x) + __expf(q[6].y);
            }
        }
        lo += __expf(q[7].x) + __expf(q[7].y);       // k=7: rev tokens 36..99 -> lo
        {   // k=8: rev tokens 2*l32+100 / +101; token 100 -> lo (lane 0 only)
            const float ex = __expf(q[8].x), ey = __expf(q[8].y);
            if (l32 == 0) lo += ex; else hi += ex;
            hi += ey;
        }
        if (l32 < 21) hi += __expf(q[9].x) + __expf(q[9].y);  // tokens 164..205

        // ---- 5-level half-wave butterfly (serves both rows at once) ------
        #pragma unroll
        for (int off = 16; off >= 1; off >>= 1) {
            const float av = __shfl_xor(aM, off);
            const int   ai = __shfl_xor(aI, off);
            if (av > aM) { aM = av; aI = ai; }
            const float sv = __shfl_xor(sM, off);
            const int   si = __shfl_xor(sI, off);
            if (sv > sM) { sM = sv; sI = si; }
            lo += __shfl_xor(lo, off);
            hi += __shfl_xor(hi, off);
        }

        // ---- per-row losses (uniform within each half) -------------------
        const float Z    = lo + hi;
        const float pno  = lo / Z;
        const float prv  = hi / Z;
        const float ai_f = (float)aI;
        const float si_f = (float)sI;
        const float pa   = (ai_f > 101.f) ? (ai_f * (1.f / 101.f) - 1.f)
                                          : (1.f - ai_f * (1.f / 101.f));
        const float ps   = si_f * (1.f / 101.f) - 1.f;
        const float da   = pa - ga;
        const float dsv  = ps - gs;
        const float ada  = fabsf(da), ads = fabsf(dsv);
        accS   += (ada < 1.f) ? 0.5f * da * da   : ada - 0.5f;
        steerS += (ads < 1.f) ? 0.5f * dsv * dsv : ads - 0.5f;
        if (gt != -100) {
            const float m2 = fmaxf(pno, prv);
            revS += m2 + __logf(__expf(pno - m2) + __expf(prv - m2))
                    - ((gt == 0) ? pno : prv);
            cntS += 1.f;
        }
    }

    // combine the two halves (each half holds its own rows' sums, uniform)
    accS   += __shfl_xor(accS, 32);
    steerS += __shfl_xor(steerS, 32);
    revS   += __shfl_xor(revS, 32);
    cntS   += __shfl_xor(cntS, 32);

    __shared__ float red[4][4];
    if (lane == 0) {
        red[wid][0] = accS; red[wid][1] = steerS;
        red[wid][2] = revS; red[wid][3] = cntS;
    }
    __syncthreads();
    if (threadIdx.x == 0) {
        double a = 0, st = 0, r = 0, c = 0;
        for (int w = 0; w < 4; ++w) {
            a += red[w][0]; st += red[w][1]; r += red[w][2]; c += red[w][3];
        }
        atomicAdd(&ws[0], a);
        atomicAdd(&ws[1], st);
        atomicAdd(&ws[2], r);
        atomicAdd(&ws[3], c);
    }
}

__global__ void control_val_loss_init(double* __restrict__ ws) {
    if (threadIdx.x < 4) ws[threadIdx.x] = 0.0;
}

__global__ void control_val_loss_final(const double* __restrict__ ws,
                                       float* __restrict__ out) {
    if (threadIdx.x == 0 && blockIdx.x == 0) {
        const double n = (double)NROWS;
        out[0] = (float)(ws[0] / n + ws[1] / n);
        out[1] = (float)(ws[2] / fmax(ws[3], 1.0));
    }
}

extern "C" void kernel_launch(void* const* d_in, const int* in_sizes, int n_in,
                              void* d_out, int out_size, void* d_ws, size_t ws_size,
                              hipStream_t stream) {
    const float* pred     = (const float*)d_in[0];
    const float* gt_acc   = (const float*)d_in[1];
    const float* gt_steer = (const float*)d_in[2];
    const int*   gt_rev   = (const int*)d_in[3];
    double* ws  = (double*)d_ws;
    float*  out = (float*)d_out;

    control_val_loss_init<<<1, 64, 0, stream>>>(ws);
    control_val_loss_main<<<2048, 256, 0, stream>>>(pred, gt_acc, gt_steer, gt_rev, ws);
    control_val_loss_final<<<1, 64, 0, stream>>>(ws, out);
}

// Round 3
// 144.350 us; speedup vs baseline: 1.2203x; 1.0257x over previous
//
#include <hip/hip_runtime.h>
#include <cstddef>

namespace {
constexpr int TOK    = 206;
constexpr int NROWS  = 256 * 682;      // 174592
constexpr int NG     = NROWS / 2;      // 87296 row-pairs
constexpr int NBLK   = 2048;
constexpr int NWAVES = NBLK * 4;       // 8192
}

struct RowData {
    float2 q[10];
    float  ga, gs;
    int    gt;
};

__device__ __forceinline__ void load_pair(
    const float* __restrict__ pred,
    const float* __restrict__ gt_acc,
    const float* __restrict__ gt_steer,
    const int*  __restrict__ gt_rev,
    int g, int h, int l32, RowData& r)
{
    const int row = 2 * g + h;
    const unsigned b = (unsigned)row / 682u;               // magic-mul div
    // (b*2048 + 3s)*206 with s = row-682b  ->  (3*row + 2*b)*206
    const float* base = pred + (size_t)(3u * (unsigned)row + 2u * b) * TOK;
    #pragma unroll
    for (int k = 0; k < 9; ++k)
        r.q[k] = *(const float2*)(base + 2 * (l32 + 32 * k));
    r.q[9] = make_float2(0.f, 0.f);
    if (l32 < 21) r.q[9] = *(const float2*)(base + 2 * (l32 + 288));
    r.gt = gt_rev[row];
    r.ga = gt_acc[row];
    r.gs = gt_steer[row];
}

__device__ __forceinline__ void compute_pair(
    const RowData& r, int l32,
    float& accS, float& steerS, float& revS, float& cntS)
{
    // ---- per-lane partials ------------------------------------------------
    float aM = r.q[0].x; int aI = 2 * l32;
    if (r.q[0].y > aM) { aM = r.q[0].y; aI = 2 * l32 + 1; }
    #pragma unroll
    for (int k = 1; k <= 2; ++k) {
        const int t = 2 * (l32 + 32 * k);
        if (r.q[k].x > aM) { aM = r.q[k].x; aI = t; }
        if (r.q[k].y > aM) { aM = r.q[k].y; aI = t + 1; }
    }
    float sM = -INFINITY; int sI = 0;
    {   // k=3: i2 in [96,128): acc if i2<103 (l32<7) else steer token 2*i2-206
        const int i2 = l32 + 96;
        if (l32 < 7) {
            if (r.q[3].x > aM) { aM = r.q[3].x; aI = 2 * i2; }
            if (r.q[3].y > aM) { aM = r.q[3].y; aI = 2 * i2 + 1; }
        } else {
            sM = r.q[3].x; sI = 2 * i2 - 206;
            if (r.q[3].y > sM) { sM = r.q[3].y; sI = 2 * i2 - 205; }
        }
    }
    #pragma unroll
    for (int k = 4; k <= 5; ++k) {       // steer tokens [50,178)
        const int st = 2 * (l32 + 32 * k) - 206;
        if (r.q[k].x > sM) { sM = r.q[k].x; sI = st; }
        if (r.q[k].y > sM) { sM = r.q[k].y; sI = st + 1; }
    }
    float lo = 0.f, hi = 0.f;
    {   // k=6: steer if l32<14 else rev (all -> lo)
        if (l32 < 14) {
            const int st = 2 * (l32 + 192) - 206;
            if (r.q[6].x > sM) { sM = r.q[6].x; sI = st; }
            if (r.q[6].y > sM) { sM = r.q[6].y; sI = st + 1; }
        } else {
            lo += __expf(r.q[6].x) + __expf(r.q[6].y);
        }
    }
    lo += __expf(r.q[7].x) + __expf(r.q[7].y);   // rev tokens 36..99 -> lo
    {   // k=8: rev tokens 2*l32+100 / +101; token 100 -> lo (lane 0 only)
        const float ex = __expf(r.q[8].x), ey = __expf(r.q[8].y);
        if (l32 == 0) lo += ex; else hi += ex;
        hi += ey;
    }
    if (l32 < 21) hi += __expf(r.q[9].x) + __expf(r.q[9].y);  // tokens 164..205

    // ---- 5-level half-wave butterfly (both rows reduced at once) ---------
    #pragma unroll
    for (int off = 16; off >= 1; off >>= 1) {
        const float av = __shfl_xor(aM, off);
        const int   ai = __shfl_xor(aI, off);
        if (av > aM) { aM = av; aI = ai; }
        const float sv = __shfl_xor(sM, off);
        const int   si = __shfl_xor(sI, off);
        if (sv > sM) { sM = sv; sI = si; }
        lo += __shfl_xor(lo, off);
        hi += __shfl_xor(hi, off);
    }

    // ---- per-row losses (uniform within each half) -----------------------
    const float Z    = lo + hi;
    const float pno  = lo / Z;
    const float prv  = hi / Z;
    const float ai_f = (float)aI;
    const float si_f = (float)sI;
    const float pa   = (ai_f > 101.f) ? (ai_f * (1.f / 101.f) - 1.f)
                                      : (1.f - ai_f * (1.f / 101.f));
    const float ps   = si_f * (1.f / 101.f) - 1.f;
    const float da   = pa - r.ga;
    const float dsv  = ps - r.gs;
    const float ada  = fabsf(da), ads = fabsf(dsv);
    accS   += (ada < 1.f) ? 0.5f * da * da   : ada - 0.5f;
    steerS += (ads < 1.f) ? 0.5f * dsv * dsv : ads - 0.5f;
    if (r.gt != -100) {
        const float m2 = fmaxf(pno, prv);
        revS += m2 + __logf(__expf(pno - m2) + __expf(prv - m2))
                - ((r.gt == 0) ? pno : prv);
        cntS += 1.f;
    }
}

__global__ __launch_bounds__(256) void control_val_loss_main(
    const float* __restrict__ pred,
    const float* __restrict__ gt_acc,
    const float* __restrict__ gt_steer,
    const int*  __restrict__ gt_rev,
    double* __restrict__ ws)
{
    const int lane = threadIdx.x & 63;
    const int wid  = threadIdx.x >> 6;
    const int l32  = lane & 31;
    const int h    = lane >> 5;
    const int gw   = blockIdx.x * 4 + wid;

    float accS = 0.f, steerS = 0.f, revS = 0.f, cntS = 0.f;

    RowData A, B;
    int g = gw;
    if (g < NG) {
        // 2-deep software pipeline: next pair's loads are in flight while
        // the current pair's butterfly/loss chain executes.
        load_pair(pred, gt_acc, gt_steer, gt_rev, g, h, l32, A);
        while (true) {
            const int g2 = g + NWAVES;
            const bool v2 = g2 < NG;
            if (v2) load_pair(pred, gt_acc, gt_steer, gt_rev, g2, h, l32, B);
            compute_pair(A, l32, accS, steerS, revS, cntS);
            if (!v2) break;
            const int g3 = g2 + NWAVES;
            const bool v3 = g3 < NG;
            if (v3) load_pair(pred, gt_acc, gt_steer, gt_rev, g3, h, l32, A);
            compute_pair(B, l32, accS, steerS, revS, cntS);
            if (!v3) break;
            g = g3;
        }
    }

    // combine the two half-wave rows
    accS   += __shfl_xor(accS, 32);
    steerS += __shfl_xor(steerS, 32);
    revS   += __shfl_xor(revS, 32);
    cntS   += __shfl_xor(cntS, 32);

    __shared__ float red[4][4];
    if (lane == 0) {
        red[wid][0] = accS; red[wid][1] = steerS;
        red[wid][2] = revS; red[wid][3] = cntS;
    }
    __syncthreads();
    if (threadIdx.x == 0) {
        double a = 0, st = 0, r = 0, c = 0;
        for (int w = 0; w < 4; ++w) {
            a += red[w][0]; st += red[w][1]; r += red[w][2]; c += red[w][3];
        }
        atomicAdd(&ws[0], a);
        atomicAdd(&ws[1], st);
        atomicAdd(&ws[2], r);
        atomicAdd(&ws[3], c);
    }
}

__global__ void control_val_loss_init(double* __restrict__ ws) {
    if (threadIdx.x < 4) ws[threadIdx.x] = 0.0;
}

__global__ void control_val_loss_final(const double* __restrict__ ws,
                                       float* __restrict__ out) {
    if (threadIdx.x == 0 && blockIdx.x == 0) {
        const double n = (double)NROWS;
        out[0] = (float)(ws[0] / n + ws[1] / n);
        out[1] = (float)(ws[2] / fmax(ws[3], 1.0));
    }
}

extern "C" void kernel_launch(void* const* d_in, const int* in_sizes, int n_in,
                              void* d_out, int out_size, void* d_ws, size_t ws_size,
                              hipStream_t stream) {
    const float* pred     = (const float*)d_in[0];
    const float* gt_acc   = (const float*)d_in[1];
    const float* gt_steer = (const float*)d_in[2];
    const int*   gt_rev   = (const int*)d_in[3];
    double* ws  = (double*)d_ws;
    float*  out = (float*)d_out;

    control_val_loss_init<<<1, 64, 0, stream>>>(ws);
    control_val_loss_main<<<NBLK, 256, 0, stream>>>(pred, gt_acc, gt_steer, gt_rev, ws);
    control_val_loss_final<<<1, 64, 0, stream>>>(ws, out);
}

// Round 4
// 89.993 us; speedup vs baseline: 1.9573x; 1.6040x over previous
//
#include <hip/hip_runtime.h>
#include <cstddef>

namespace {
constexpr int TOK    = 206;
constexpr int NROWS  = 256 * 682;        // 174592
constexpr int R      = 8;                // rows per block (174592 % 8 == 0)
constexpr int NBLK   = NROWS / R;        // 21824
constexpr int LROW2  = 310;              // float2 slots per LDS row (309 + 1)
constexpr int LDSF2  = R * LROW2 + 16;   // + tail pad for unconditional q[9] reads
constexpr int NSLOT  = 64;               // atomic spread slots
}

__global__ __launch_bounds__(256) void cvl_main(
    const float* __restrict__ pred,
    const float* __restrict__ gt_acc,
    const float* __restrict__ gt_steer,
    const int*  __restrict__ gt_rev,
    double* __restrict__ ws)
{
    __shared__ double lds2[LDSF2];       // float2 payloads held as 8B doubles

    const int tid = threadIdx.x;
    const int r0  = blockIdx.x * R;

    // ---- stage 8 rows -> LDS: flat independent nontemporal 8B loads ------
    const double* srcs[R];
    #pragma unroll
    for (int r = 0; r < R; ++r) {
        const int row = r0 + r;
        const unsigned bb = (unsigned)row / 682u;            // magic-mul div
        // float offset (b*2048 + 3s)*206 == (3*row + 2*b)*206
        srcs[r] = (const double*)(pred + (size_t)(3u * (unsigned)row + 2u * bb) * TOK);
    }
    double va[R], vb[R];
    #pragma unroll
    for (int r = 0; r < R; ++r) va[r] = __builtin_nontemporal_load(srcs[r] + tid);
    const bool tail = (tid < 53);                            // 309 = 256 + 53
    if (tail) {
        #pragma unroll
        for (int r = 0; r < R; ++r) vb[r] = __builtin_nontemporal_load(srcs[r] + 256 + tid);
    }
    #pragma unroll
    for (int r = 0; r < R; ++r) lds2[r * LROW2 + tid] = va[r];
    if (tail) {
        #pragma unroll
        for (int r = 0; r < R; ++r) lds2[r * LROW2 + 256 + tid] = vb[r];
    }
    __syncthreads();

    // ---- compute: wave w handles row-pair (2w, 2w+1); half-wave per row --
    const int lane = tid & 63;
    const int wid  = tid >> 6;
    const int l32  = lane & 31;
    const int h    = lane >> 5;
    const int rloc = 2 * wid + h;
    const int row  = r0 + rloc;
    const double* rp = &lds2[rloc * LROW2];

    float2 q[10];
    #pragma unroll
    for (int k = 0; k < 10; ++k)
        q[k] = __builtin_bit_cast(float2, rp[l32 + 32 * k]);  // k=9 OOB lanes: pad, masked below

    const int   gt = gt_rev[row];
    const float ga = gt_acc[row];
    const float gs = gt_steer[row];

    // per-lane partials (verified mapping from R2, absmax 0.0)
    float aM = q[0].x; int aI = 2 * l32;
    if (q[0].y > aM) { aM = q[0].y; aI = 2 * l32 + 1; }
    #pragma unroll
    for (int k = 1; k <= 2; ++k) {
        const int t = 2 * (l32 + 32 * k);
        if (q[k].x > aM) { aM = q[k].x; aI = t; }
        if (q[k].y > aM) { aM = q[k].y; aI = t + 1; }
    }
    float sM = -INFINITY; int sI = 0;
    {   // k=3: i2 in [96,128): acc if i2<103 (l32<7) else steer token 2*i2-206
        const int i2 = l32 + 96;
        if (l32 < 7) {
            if (q[3].x > aM) { aM = q[3].x; aI = 2 * i2; }
            if (q[3].y > aM) { aM = q[3].y; aI = 2 * i2 + 1; }
        } else {
            sM = q[3].x; sI = 2 * i2 - 206;
            if (q[3].y > sM) { sM = q[3].y; sI = 2 * i2 - 205; }
        }
    }
    #pragma unroll
    for (int k = 4; k <= 5; ++k) {       // steer tokens [50,178)
        const int st = 2 * (l32 + 32 * k) - 206;
        if (q[k].x > sM) { sM = q[k].x; sI = st; }
        if (q[k].y > sM) { sM = q[k].y; sI = st + 1; }
    }
    float lo = 0.f, hi = 0.f;
    {   // k=6: steer if l32<14 else rev (-> lo)
        if (l32 < 14) {
            const int st = 2 * (l32 + 192) - 206;
            if (q[6].x > sM) { sM = q[6].x; sI = st; }
            if (q[6].y > sM) { sM = q[6].y; sI = st + 1; }
        } else {
            lo += __expf(q[6].x) + __expf(q[6].y);
        }
    }
    lo += __expf(q[7].x) + __expf(q[7].y);           // rev tokens 36..99
    {   // k=8: rev tokens 2*l32+100 / +101
        const float ex = __expf(q[8].x), ey = __expf(q[8].y);
        if (l32 == 0) lo += ex; else hi += ex;
        hi += ey;
    }
    if (l32 < 21) hi += __expf(q[9].x) + __expf(q[9].y);  // rev tokens 164..205

    // 5-level half-wave butterfly (reduces both rows at once)
    #pragma unroll
    for (int off = 16; off >= 1; off >>= 1) {
        const float av = __shfl_xor(aM, off);
        const int   ai = __shfl_xor(aI, off);
        if (av > aM) { aM = av; aI = ai; }
        const float sv = __shfl_xor(sM, off);
        const int   si = __shfl_xor(sI, off);
        if (sv > sM) { sM = sv; sI = si; }
        lo += __shfl_xor(lo, off);
        hi += __shfl_xor(hi, off);
    }

    // per-row losses (uniform within each half)
    float accS, steerS, revS = 0.f, cntS = 0.f;
    {
        const float Z    = lo + hi;
        const float pno  = lo / Z;
        const float prv  = hi / Z;
        const float ai_f = (float)aI;
        const float si_f = (float)sI;
        const float pa   = (ai_f > 101.f) ? (ai_f * (1.f / 101.f) - 1.f)
                                          : (1.f - ai_f * (1.f / 101.f));
        const float ps   = si_f * (1.f / 101.f) - 1.f;
        const float da   = pa - ga;
        const float dsv  = ps - gs;
        const float ada  = fabsf(da), ads = fabsf(dsv);
        accS   = (ada < 1.f) ? 0.5f * da * da   : ada - 0.5f;
        steerS = (ads < 1.f) ? 0.5f * dsv * dsv : ads - 0.5f;
        if (gt != -100) {
            const float m2 = fmaxf(pno, prv);
            revS = m2 + __logf(__expf(pno - m2) + __expf(prv - m2))
                   - ((gt == 0) ? pno : prv);
            cntS = 1.f;
        }
    }

    // combine the two half-wave rows -> per-wave pair totals
    accS   += __shfl_xor(accS, 32);
    steerS += __shfl_xor(steerS, 32);
    revS   += __shfl_xor(revS, 32);
    cntS   += __shfl_xor(cntS, 32);

    __shared__ float red[4][4];
    if (lane == 0) {
        red[wid][0] = accS; red[wid][1] = steerS;
        red[wid][2] = revS; red[wid][3] = cntS;
    }
    __syncthreads();
    if (tid == 0) {
        double a = 0, st = 0, rr = 0, c = 0;
        for (int w = 0; w < 4; ++w) {
            a += red[w][0]; st += red[w][1]; rr += red[w][2]; c += red[w][3];
        }
        double* slot = ws + (size_t)(blockIdx.x & (NSLOT - 1)) * 4;
        atomicAdd(slot + 0, a);
        atomicAdd(slot + 1, st);
        atomicAdd(slot + 2, rr);
        atomicAdd(slot + 3, c);
    }
}

__global__ void cvl_init(double* __restrict__ ws) {
    const int i = blockIdx.x * blockDim.x + threadIdx.x;
    if (i < NSLOT * 4) ws[i] = 0.0;
}

__global__ void cvl_final(const double* __restrict__ ws, float* __restrict__ out) {
    const int t = threadIdx.x;          // 64 threads, one slot each
    double a = ws[4 * t], st = ws[4 * t + 1], r = ws[4 * t + 2], c = ws[4 * t + 3];
    #pragma unroll
    for (int off = 32; off >= 1; off >>= 1) {
        a  += __shfl_xor(a,  off);
        st += __shfl_xor(st, off);
        r  += __shfl_xor(r,  off);
        c  += __shfl_xor(c,  off);
    }
    if (t == 0) {
        const double n = (double)NROWS;
        out[0] = (float)(a / n + st / n);
        out[1] = (float)(r / fmax(c, 1.0));
    }
}

extern "C" void kernel_launch(void* const* d_in, const int* in_sizes, int n_in,
                              void* d_out, int out_size, void* d_ws, size_t ws_size,
                              hipStream_t stream) {
    const float* pred     = (const float*)d_in[0];
    const float* gt_acc   = (const float*)d_in[1];
    const float* gt_steer = (const float*)d_in[2];
    const int*   gt_rev   = (const int*)d_in[3];
    double* ws  = (double*)d_ws;
    float*  out = (float*)d_out;

    cvl_init<<<1, 256, 0, stream>>>(ws);
    cvl_main<<<NBLK, 256, 0, stream>>>(pred, gt_acc, gt_steer, gt_rev, ws);
    cvl_final<<<1, 64, 0, stream>>>(ws, out);
}

// Round 6
// 86.787 us; speedup vs baseline: 2.0296x; 1.0369x over previous
//
#include <hip/hip_runtime.h>
#include <cstddef>

namespace {
constexpr int TOK   = 206;
constexpr int NROWS = 256 * 682;        // 174592
constexpr int R     = 8;                // rows per block (174592 % 8 == 0)
constexpr int NBLK  = NROWS / R;        // 21824
constexpr int LROW2 = 310;              // doubles per LDS row (309 + 1); 2480B stride, 16B-aligned
constexpr int LDSF2 = R * LROW2 + 16;   // + tail pad for unconditional q[9] reads
constexpr int NSLOT = 64;               // atomic spread slots
}

typedef float f32x4 __attribute__((ext_vector_type(4)));

__global__ __launch_bounds__(256) void cvl_main(
    const float* __restrict__ pred,
    const float* __restrict__ gt_acc,
    const float* __restrict__ gt_steer,
    const int*  __restrict__ gt_rev,
    double* __restrict__ ws)
{
    __shared__ alignas(16) double lds2[LDSF2];

    const int tid = threadIdx.x;
    const int r0  = blockIdx.x * R;

    // ---- stage 8 rows -> LDS: 32 threads/row, 16B nontemporal loads ------
    // staging row sr == compute row rloc for this thread (tid>>5 == 2*wid+h)
    const int sr = tid >> 5;
    const int sc = tid & 31;
    const int row = r0 + sr;
    const unsigned bb = (unsigned)row / 682u;            // magic-mul div
    // float offset (b*2048 + 3s)*206 == (3*row + 2*b)*206
    const float* base = pred + (size_t)(3u * (unsigned)row + 2u * bb) * TOK;

    // issue all global loads back-to-back (deep MLP), incl. gt_* for compute
    f32x4 v[5];
    #pragma unroll
    for (int k = 0; k < 4; ++k)
        v[k] = __builtin_nontemporal_load((const f32x4*)base + sc + 32 * k);
    const bool t5 = (sc < 26);                           // 154 = 4*32 + 26
    f32x4 v4 = (f32x4){0.f, 0.f, 0.f, 0.f};
    if (t5) v4 = __builtin_nontemporal_load((const f32x4*)base + sc + 128);
    double tl = 0.0;
    if (sc == 31)                                        // row floats [616,618)
        tl = __builtin_nontemporal_load((const double*)(base + 616));
    const int   gt = gt_rev[row];
    const float ga = gt_acc[row];
    const float gs = gt_steer[row];

    // LDS writes: b128, consecutive-per-lane (standard conflict-free pattern)
    f32x4* lrow4 = (f32x4*)(lds2 + sr * LROW2);
    #pragma unroll
    for (int k = 0; k < 4; ++k) lrow4[sc + 32 * k] = v[k];
    if (t5) lrow4[sc + 128] = v4;
    if (sc == 31) lds2[sr * LROW2 + 308] = tl;
    __syncthreads();

    // ---- compute: wave wid handles rows (2wid, 2wid+1); half-wave per row
    const int lane = tid & 63;
    const int wid  = tid >> 6;
    const int l32  = lane & 31;
    const double* rp = &lds2[sr * LROW2];                // sr == rloc

    float2 q[10];
    #pragma unroll
    for (int k = 0; k < 10; ++k)
        q[k] = __builtin_bit_cast(float2, rp[l32 + 32 * k]);  // k=9 OOB lanes: pad, masked

    // per-lane partials (verified mapping, absmax 0.0 since R2)
    float aM = q[0].x; int aI = 2 * l32;
    if (q[0].y > aM) { aM = q[0].y; aI = 2 * l32 + 1; }
    #pragma unroll
    for (int k = 1; k <= 2; ++k) {
        const int t = 2 * (l32 + 32 * k);
        if (q[k].x > aM) { aM = q[k].x; aI = t; }
        if (q[k].y > aM) { aM = q[k].y; aI = t + 1; }
    }
    float sM = -INFINITY; int sI = 0;
    {   // k=3: i2 in [96,128): acc if i2<103 (l32<7) else steer token 2*i2-206
        const int i2 = l32 + 96;
        if (l32 < 7) {
            if (q[3].x > aM) { aM = q[3].x; aI = 2 * i2; }
            if (q[3].y > aM) { aM = q[3].y; aI = 2 * i2 + 1; }
        } else {
            sM = q[3].x; sI = 2 * i2 - 206;
            if (q[3].y > sM) { sM = q[3].y; sI = 2 * i2 - 205; }
        }
    }
    #pragma unroll
    for (int k = 4; k <= 5; ++k) {       // steer tokens [50,178)
        const int st = 2 * (l32 + 32 * k) - 206;
        if (q[k].x > sM) { sM = q[k].x; sI = st; }
        if (q[k].y > sM) { sM = q[k].y; sI = st + 1; }
    }
    float lo = 0.f, hi = 0.f;
    {   // k=6: steer if l32<14 else rev (-> lo)
        if (l32 < 14) {
            const int st = 2 * (l32 + 192) - 206;
            if (q[6].x > sM) { sM = q[6].x; sI = st; }
            if (q[6].y > sM) { sM = q[6].y; sI = st + 1; }
        } else {
            lo += __expf(q[6].x) + __expf(q[6].y);
        }
    }
    lo += __expf(q[7].x) + __expf(q[7].y);               // rev tokens 36..99
    {   // k=8: rev tokens 2*l32+100 / +101
        const float ex = __expf(q[8].x), ey = __expf(q[8].y);
        if (l32 == 0) lo += ex; else hi += ex;
        hi += ey;
    }
    if (l32 < 21) hi += __expf(q[9].x) + __expf(q[9].y); // rev tokens 164..205

    // 5-level half-wave butterfly (reduces both rows at once)
    #pragma unroll
    for (int off = 16; off >= 1; off >>= 1) {
        const float av = __shfl_xor(aM, off);
        const int   ai = __shfl_xor(aI, off);
        if (av > aM) { aM = av; aI = ai; }
        const float sv = __shfl_xor(sM, off);
        const int   si = __shfl_xor(sI, off);
        if (sv > sM) { sM = sv; sI = si; }
        lo += __shfl_xor(lo, off);
        hi += __shfl_xor(hi, off);
    }

    // per-row losses (uniform within each half)
    float accS, steerS, revS = 0.f, cntS = 0.f;
    {
        const float Z    = lo + hi;
        const float pno  = lo / Z;
        const float prv  = hi / Z;
        const float ai_f = (float)aI;
        const float si_f = (float)sI;
        const float pa   = (ai_f > 101.f) ? (ai_f * (1.f / 101.f) - 1.f)
                                          : (1.f - ai_f * (1.f / 101.f));
        const float ps   = si_f * (1.f / 101.f) - 1.f;
        const float da   = pa - ga;
        const float dsv  = ps - gs;
        const float ada  = fabsf(da), ads = fabsf(dsv);
        accS   = (ada < 1.f) ? 0.5f * da * da   : ada - 0.5f;
        steerS = (ads < 1.f) ? 0.5f * dsv * dsv : ads - 0.5f;
        if (gt != -100) {
            const float m2 = fmaxf(pno, prv);
            revS = m2 + __logf(__expf(pno - m2) + __expf(prv - m2))
                   - ((gt == 0) ? pno : prv);
            cntS = 1.f;
        }
    }

    // combine the two half-wave rows -> per-wave pair totals
    accS   += __shfl_xor(accS, 32);
    steerS += __shfl_xor(steerS, 32);
    revS   += __shfl_xor(revS, 32);
    cntS   += __shfl_xor(cntS, 32);

    __shared__ float red[4][4];
    if (lane == 0) {
        red[wid][0] = accS; red[wid][1] = steerS;
        red[wid][2] = revS; red[wid][3] = cntS;
    }
    __syncthreads();
    if (tid == 0) {
        double a = 0, st = 0, rr = 0, c = 0;
        for (int w = 0; w < 4; ++w) {
            a += red[w][0]; st += red[w][1]; rr += red[w][2]; c += red[w][3];
        }
        double* slot = ws + (size_t)(blockIdx.x & (NSLOT - 1)) * 4;
        atomicAdd(slot + 0, a);
        atomicAdd(slot + 1, st);
        atomicAdd(slot + 2, rr);
        atomicAdd(slot + 3, c);
    }
}

__global__ void cvl_init(double* __restrict__ ws) {
    const int i = blockIdx.x * blockDim.x + threadIdx.x;
    if (i < NSLOT * 4) ws[i] = 0.0;
}

__global__ void cvl_final(const double* __restrict__ ws, float* __restrict__ out) {
    const int t = threadIdx.x;           // 64 threads, one slot each
    double a = ws[4 * t], st = ws[4 * t + 1], r = ws[4 * t + 2], c = ws[4 * t + 3];
    #pragma unroll
    for (int off = 32; off >= 1; off >>= 1) {
        a  += __shfl_xor(a,  off);
        st += __shfl_xor(st, off);
        r  += __shfl_xor(r,  off);
        c  += __shfl_xor(c,  off);
    }
    if (t == 0) {
        const double n = (double)NROWS;
        out[0] = (float)(a / n + st / n);
        out[1] = (float)(r / fmax(c, 1.0));
    }
}

extern "C" void kernel_launch(void* const* d_in, const int* in_sizes, int n_in,
                              void* d_out, int out_size, void* d_ws, size_t ws_size,
                              hipStream_t stream) {
    const float* pred     = (const float*)d_in[0];
    const float* gt_acc   = (const float*)d_in[1];
    const float* gt_steer = (const float*)d_in[2];
    const int*   gt_rev   = (const int*)d_in[3];
    double* ws  = (double*)d_ws;
    float*  out = (float*)d_out;

    cvl_init<<<1, 256, 0, stream>>>(ws);
    cvl_main<<<NBLK, 256, 0, stream>>>(pred, gt_acc, gt_steer, gt_rev, ws);
    cvl_final<<<1, 64, 0, stream>>>(ws, out);
}

// Round 7
// 82.373 us; speedup vs baseline: 2.1384x; 1.0536x over previous
//
#include <hip/hip_runtime.h>
#include <cstddef>

namespace {
constexpr int TOK   = 206;
constexpr int NROWS = 256 * 682;        // 174592
constexpr int R     = 8;                // rows per group (174592 % 8 == 0)
constexpr int NGRP  = NROWS / R;        // 21824 groups
constexpr int GRID  = 2048;             // persistent blocks, grid-stride over groups
constexpr int LROW2 = 310;              // doubles per LDS row; 2480B stride, 16B-aligned
constexpr int LDSF2 = R * LROW2 + 16;   // + tail pad for unconditional q[9] reads
constexpr int NSLOT = 64;               // atomic spread slots
}

typedef float f32x4 __attribute__((ext_vector_type(4)));

__global__ __launch_bounds__(256) void cvl_main(
    const float* __restrict__ pred,
    const float* __restrict__ gt_acc,
    const float* __restrict__ gt_steer,
    const int*  __restrict__ gt_rev,
    double* __restrict__ ws)
{
    __shared__ alignas(16) double lds2[LDSF2];

    const int tid = threadIdx.x;
    const int sr  = tid >> 5;            // staging row == compute row for this thread
    const int sc  = tid & 31;
    const int lane = tid & 63;
    const int wid  = tid >> 6;
    const int l32  = lane & 31;

    float accS = 0.f, steerS = 0.f, revS = 0.f, cntS = 0.f;

    // ---- group-load: issue all global loads back-to-back (no consumers) --
    f32x4 v[5];
    double tl = 0.0;
    int   gtN; float gaN, gsN;
    auto load_group = [&](int g) {
        const int row = g * R + sr;
        const unsigned bb = (unsigned)row / 682u;        // magic-mul div
        // float offset (b*2048 + 3s)*206 == (3*row + 2*b)*206
        const float* base = pred + (size_t)(3u * (unsigned)row + 2u * bb) * TOK;
        #pragma unroll
        for (int k = 0; k < 4; ++k)
            v[k] = __builtin_nontemporal_load((const f32x4*)base + sc + 32 * k);
        if (sc < 26)                                     // 154 = 4*32 + 26
            v[4] = __builtin_nontemporal_load((const f32x4*)base + sc + 128);
        if (sc == 31)                                    // row floats [616,618)
            tl = __builtin_nontemporal_load((const double*)(base + 616));
        gtN = gt_rev[row];
        gaN = gt_acc[row];
        gsN = gt_steer[row];
    };

    int g = blockIdx.x;
    if (g < NGRP) load_group(g);

    while (g < NGRP) {
        // regs hold group g: write -> LDS (vmcnt wait lands the loads)
        f32x4* lrow4 = (f32x4*)(lds2 + sr * LROW2);
        #pragma unroll
        for (int k = 0; k < 4; ++k) lrow4[sc + 32 * k] = v[k];
        if (sc < 26) lrow4[sc + 128] = v[4];
        if (sc == 31) lds2[sr * LROW2 + 308] = tl;
        const int   gt = gtN;
        const float ga = gaN;
        const float gs = gsN;
        __syncthreads();

        // issue NEXT group's loads now — in flight during compute below
        const int gn = g + GRID;
        if (gn < NGRP) load_group(gn);

        // ---- compute group g from LDS (verified mapping, absmax 0.0) ----
        const double* rp = &lds2[sr * LROW2];
        float2 q[10];
        #pragma unroll
        for (int k = 0; k < 10; ++k)
            q[k] = __builtin_bit_cast(float2, rp[l32 + 32 * k]); // k=9 OOB lanes: pad, masked

        float aM = q[0].x; int aI = 2 * l32;
        if (q[0].y > aM) { aM = q[0].y; aI = 2 * l32 + 1; }
        #pragma unroll
        for (int k = 1; k <= 2; ++k) {
            const int t = 2 * (l32 + 32 * k);
            if (q[k].x > aM) { aM = q[k].x; aI = t; }
            if (q[k].y > aM) { aM = q[k].y; aI = t + 1; }
        }
        float sM = -INFINITY; int sI = 0;
        {   // k=3: acc if l32<7 else steer token 2*i2-206
            const int i2 = l32 + 96;
            if (l32 < 7) {
                if (q[3].x > aM) { aM = q[3].x; aI = 2 * i2; }
                if (q[3].y > aM) { aM = q[3].y; aI = 2 * i2 + 1; }
            } else {
                sM = q[3].x; sI = 2 * i2 - 206;
                if (q[3].y > sM) { sM = q[3].y; sI = 2 * i2 - 205; }
            }
        }
        #pragma unroll
        for (int k = 4; k <= 5; ++k) {   // steer tokens [50,178)
            const int st = 2 * (l32 + 32 * k) - 206;
            if (q[k].x > sM) { sM = q[k].x; sI = st; }
            if (q[k].y > sM) { sM = q[k].y; sI = st + 1; }
        }
        float lo = 0.f, hi = 0.f;
        {   // k=6: steer if l32<14 else rev (-> lo)
            if (l32 < 14) {
                const int st = 2 * (l32 + 192) - 206;
                if (q[6].x > sM) { sM = q[6].x; sI = st; }
                if (q[6].y > sM) { sM = q[6].y; sI = st + 1; }
            } else {
                lo += __expf(q[6].x) + __expf(q[6].y);
            }
        }
        lo += __expf(q[7].x) + __expf(q[7].y);           // rev tokens 36..99
        {   // k=8: rev tokens 2*l32+100 / +101
            const float ex = __expf(q[8].x), ey = __expf(q[8].y);
            if (l32 == 0) lo += ex; else hi += ex;
            hi += ey;
        }
        if (l32 < 21) hi += __expf(q[9].x) + __expf(q[9].y); // rev tokens 164..205

        #pragma unroll
        for (int off = 16; off >= 1; off >>= 1) {
            const float av = __shfl_xor(aM, off);
            const int   ai = __shfl_xor(aI, off);
            if (av > aM) { aM = av; aI = ai; }
            const float sv = __shfl_xor(sM, off);
            const int   si = __shfl_xor(sI, off);
            if (sv > sM) { sM = sv; sI = si; }
            lo += __shfl_xor(lo, off);
            hi += __shfl_xor(hi, off);
        }

        {   // per-row losses (uniform within each half-wave)
            const float Z    = lo + hi;
            const float pno  = lo / Z;
            const float prv  = hi / Z;
            const float ai_f = (float)aI;
            const float si_f = (float)sI;
            const float pa   = (ai_f > 101.f) ? (ai_f * (1.f / 101.f) - 1.f)
                                              : (1.f - ai_f * (1.f / 101.f));
            const float ps   = si_f * (1.f / 101.f) - 1.f;
            const float da   = pa - ga;
            const float dsv  = ps - gs;
            const float ada  = fabsf(da), ads = fabsf(dsv);
            accS   += (ada < 1.f) ? 0.5f * da * da   : ada - 0.5f;
            steerS += (ads < 1.f) ? 0.5f * dsv * dsv : ads - 0.5f;
            if (gt != -100) {
                const float m2 = fmaxf(pno, prv);
                revS += m2 + __logf(__expf(pno - m2) + __expf(prv - m2))
                        - ((gt == 0) ? pno : prv);
                cntS += 1.f;
            }
        }
        __syncthreads();                 // done reading LDS; next write may proceed
        g = gn;
    }

    // ---- per-block tail: combine halves, waves, one atomic per block ----
    accS   += __shfl_xor(accS, 32);
    steerS += __shfl_xor(steerS, 32);
    revS   += __shfl_xor(revS, 32);
    cntS   += __shfl_xor(cntS, 32);

    __shared__ float red[4][4];
    if (lane == 0) {
        red[wid][0] = accS; red[wid][1] = steerS;
        red[wid][2] = revS; red[wid][3] = cntS;
    }
    __syncthreads();
    if (tid == 0) {
        double a = 0, st = 0, rr = 0, c = 0;
        for (int w = 0; w < 4; ++w) {
            a += red[w][0]; st += red[w][1]; rr += red[w][2]; c += red[w][3];
        }
        double* slot = ws + (size_t)(blockIdx.x & (NSLOT - 1)) * 4;
        atomicAdd(slot + 0, a);
        atomicAdd(slot + 1, st);
        atomicAdd(slot + 2, rr);
        atomicAdd(slot + 3, c);
    }
}

__global__ void cvl_init(double* __restrict__ ws) {
    const int i = blockIdx.x * blockDim.x + threadIdx.x;
    if (i < NSLOT * 4) ws[i] = 0.0;
}

__global__ void cvl_final(const double* __restrict__ ws, float* __restrict__ out) {
    const int t = threadIdx.x;           // 64 threads, one slot each
    double a = ws[4 * t], st = ws[4 * t + 1], r = ws[4 * t + 2], c = ws[4 * t + 3];
    #pragma unroll
    for (int off = 32; off >= 1; off >>= 1) {
        a  += __shfl_xor(a,  off);
        st += __shfl_xor(st, off);
        r  += __shfl_xor(r,  off);
        c  += __shfl_xor(c,  off);
    }
    if (t == 0) {
        const double n = (double)NROWS;
        out[0] = (float)(a / n + st / n);
        out[1] = (float)(r / fmax(c, 1.0));
    }
}

extern "C" void kernel_launch(void* const* d_in, const int* in_sizes, int n_in,
                              void* d_out, int out_size, void* d_ws, size_t ws_size,
                              hipStream_t stream) {
    const float* pred     = (const float*)d_in[0];
    const float* gt_acc   = (const float*)d_in[1];
    const float* gt_steer = (const float*)d_in[2];
    const int*   gt_rev   = (const int*)d_in[3];
    double* ws  = (double*)d_ws;
    float*  out = (float*)d_out;

    cvl_init<<<1, 256, 0, stream>>>(ws);
    cvl_main<<<GRID, 256, 0, stream>>>(pred, gt_acc, gt_steer, gt_rev, ws);
    cvl_final<<<1, 64, 0, stream>>>(ws, out);
}